// Round 9
// baseline (301.724 us; speedup 1.0000x reference)
//
#include <hip/hip_runtime.h>

// Problem: VoxelMorph flow pipeline.
// features [16,128,128,128] f32, moving_label [1,128,128,128] f32,
// weight [3,16,3,3,3] f32, bias [3] f32.
// Output: moved [128^3] then flow [3*128^3], f32, concatenated flat.
//
// R13. Budget model (from reconciling R2 counter-vs-bench gap): bench dur =
// device time + ~130us fixed harness overhead. Device time ~= conv 94 +
// phases ~70. Phases are already near their floor; conv is latency-bound
// (VALU 52%, HBM 24%, occ 34% = 11 waves/CU -- nothing saturated).
// R13 change: conv occupancy 4 -> 8 blocks/CU. x-tile 64 -> 32, grid 2048,
// LDS 17.95KB/block, each thread 2 z-pairs. 2048 thr/CU (HW cap), 32
// waves/CU for latency hiding. All R10 conv properties kept: x-innermost
// coalesced staging, stride-11 LDS (conflict-free), packed f32x2 FMA.
// Phases: R12's flat global passes (ds, s1..s7, f4up) -- unchanged.

#define V128 2097152      // 128^3
#define V64  262144       // 64^3

typedef __attribute__((ext_vector_type(2))) float f32x2;
typedef float f32x2u __attribute__((ext_vector_type(2), aligned(4)));

// ---------------- trilinear sampler, planar vol (label warp) ---------------
template <int C>
__device__ __forceinline__ void trisample(const float* __restrict__ vol,
                                          int D, int H, int W, int cstride,
                                          float cz, float cy, float cx,
                                          float* out) {
    float fz = floorf(cz), fy = floorf(cy), fx = floorf(cx);
    int iz = (int)fz, iy = (int)fy, ix = (int)fx;
    float tz = cz - fz, ty = cy - fy, tx = cx - fx;
#pragma unroll
    for (int c = 0; c < C; ++c) out[c] = 0.0f;
#pragma unroll
    for (int dz = 0; dz < 2; ++dz) {
#pragma unroll
        for (int dy = 0; dy < 2; ++dy) {
#pragma unroll
            for (int dx = 0; dx < 2; ++dx) {
                int z = iz + dz, y = iy + dy, x = ix + dx;
                float w = (dz ? tz : 1.0f - tz) *
                          (dy ? ty : 1.0f - ty) *
                          (dx ? tx : 1.0f - tx);
                bool valid = (z >= 0) && (z < D) && (y >= 0) && (y < H) &&
                             (x >= 0) && (x < W);
                int zc = min(max(z, 0), D - 1);
                int yc = min(max(y, 0), H - 1);
                int xc = min(max(x, 0), W - 1);
                int base = (zc * H + yc) * W + xc;
                float wv = valid ? w : 0.0f;
#pragma unroll
                for (int c = 0; c < C; ++c)
                    out[c] += vol[c * cstride + base] * wv;
            }
        }
    }
}

// ------- trilinear sampler, interleaved [vox][3] 64^3 volume, masked -------
__device__ __forceinline__ void trisample3i64(const float* __restrict__ vol,
                                              float cz, float cy, float cx,
                                              float* out) {
    float fz = floorf(cz), fy = floorf(cy), fx = floorf(cx);
    int iz = (int)fz, iy = (int)fy, ix = (int)fx;
    float tz = cz - fz, ty = cy - fy, tx = cx - fx;
    out[0] = 0.0f;
    out[1] = 0.0f;
    out[2] = 0.0f;
#pragma unroll
    for (int dz = 0; dz < 2; ++dz) {
#pragma unroll
        for (int dy = 0; dy < 2; ++dy) {
#pragma unroll
            for (int dx = 0; dx < 2; ++dx) {
                int z = iz + dz, y = iy + dy, x = ix + dx;
                float w = (dz ? tz : 1.0f - tz) *
                          (dy ? ty : 1.0f - ty) *
                          (dx ? tx : 1.0f - tx);
                bool valid = ((unsigned)z < 64u) && ((unsigned)y < 64u) &&
                             ((unsigned)x < 64u);
                int zc = min(max(z, 0), 63);
                int yc = min(max(y, 0), 63);
                int xc = min(max(x, 0), 63);
                int b3 = ((zc << 12) + (yc << 6) + xc) * 3;
                float wv = valid ? w : 0.0f;
                out[0] += vol[b3] * wv;
                out[1] += vol[b3 + 1] * wv;
                out[2] += vol[b3 + 2] * wv;
            }
        }
    }
}

// ---------------- K1: conv3d 16->3, 3x3x3, pad 1 ---------------------------
// Tile 32x4x8, grid (4,32,16)=2048 blocks, 8 blocks/CU (LDS 17.95KB).
// Staging x-innermost over 34x6x10=2040 elems (8 slots/thread, coalesced
// 34-float runs); LDS z-innermost stride-11 (bank 11*lane mod 32 bijective).
// Thread (lx,ly,lh) = (tid&31, (tid>>5)&3, tid>>7) computes 2 z-pairs at
// abs pair azp = 2*lh + zp'. Packed f32x2 z-pair FMA (v_pk_fma_f32).
__global__ __launch_bounds__(256) void conv_kernel(
    const float* __restrict__ feat, const float* __restrict__ weight,
    const float* __restrict__ bias, float* __restrict__ pf) {
    __shared__ float smem[2][2244];  // 204 columns * 11
    const int tid = threadIdx.x;
    const int x0 = blockIdx.x * 32, y0 = blockIdx.y * 4, z0 = blockIdx.z * 8;
    const int lx = tid & 31, ly = (tid >> 5) & 3, lh = tid >> 7;

    int goff[8];
    int laddr[8];
    unsigned vmask = 0;
#pragma unroll
    for (int k = 0; k < 8; ++k) {
        int s = tid + 256 * k;
        int xx = s % 34;
        int r = s / 34;
        int yy = r % 6;
        int zz = r / 6;
        laddr[k] = (yy * 34 + xx) * 11 + zz;
        bool intile = (k < 7) || (tid < 248);  // 2040 = 256*7 + 248
        int gx = x0 + xx - 1, gy = y0 + yy - 1, gz = z0 + zz - 1;
        bool ok = intile && ((unsigned)gx < 128u) && ((unsigned)gy < 128u) &&
                  ((unsigned)gz < 128u);
        goff[k] = (gz << 14) + (gy << 7) + gx;
        if (ok) vmask |= (1u << k);
    }

    f32x2 acc[3][2];
#pragma unroll
    for (int o = 0; o < 3; ++o)
#pragma unroll
        for (int zp = 0; zp < 2; ++zp) acc[o][zp] = (f32x2)(0.0f);

    {
        float vals[8];
#pragma unroll
        for (int k = 0; k < 8; ++k) {
            vals[k] = 0.0f;
            if (vmask & (1u << k)) vals[k] = feat[goff[k]];
        }
#pragma unroll
        for (int k = 0; k < 8; ++k)
            if (k < 7 || tid < 248) smem[0][laddr[k]] = vals[k];
    }

    for (int c = 0; c < 16; ++c) {
        __syncthreads();
        if (c + 1 < 16) {
            const float* fc = feat + ((c + 1) << 21);
            float* buf = smem[(c + 1) & 1];
            float vals[8];
#pragma unroll
            for (int k = 0; k < 8; ++k) {
                vals[k] = 0.0f;
                if (vmask & (1u << k)) vals[k] = fc[goff[k]];
            }
#pragma unroll
            for (int k = 0; k < 8; ++k)
                if (k < 7 || tid < 248) buf[laddr[k]] = vals[k];
        }
        const float* buf = smem[c & 1];
        const float* wc = weight + c * 27;
#pragma unroll
        for (int dy = 0; dy < 3; ++dy) {
#pragma unroll
            for (int dx = 0; dx < 3; ++dx) {
                // z range needed: [4*lh, 4*lh+5]
                const float* p =
                    buf + ((ly + dy) * 34 + lx + dx) * 11 + 4 * lh;
                f32x2 pv[3];
                f32x2 qv[2];
#pragma unroll
                for (int k2 = 0; k2 < 3; ++k2)
                    pv[k2] = *(const f32x2u*)(p + 2 * k2);
#pragma unroll
                for (int k2 = 0; k2 < 2; ++k2)
                    qv[k2] = *(const f32x2u*)(p + 2 * k2 + 1);
#pragma unroll
                for (int o = 0; o < 3; ++o) {
                    float w0 = wc[o * 432 + 0 + dy * 3 + dx];
                    float w1 = wc[o * 432 + 9 + dy * 3 + dx];
                    float w2 = wc[o * 432 + 18 + dy * 3 + dx];
#pragma unroll
                    for (int zp = 0; zp < 2; ++zp) {
                        acc[o][zp] += pv[zp] * (f32x2)(w0);
                        acc[o][zp] += qv[zp] * (f32x2)(w1);
                        acc[o][zp] += pv[zp + 1] * (f32x2)(w2);
                    }
                }
            }
        }
    }

    float b0 = bias[0], b1 = bias[1], b2 = bias[2];
#pragma unroll
    for (int zp = 0; zp < 2; ++zp) {
        int azp = 2 * lh + zp;
        int vox0 = ((z0 + 2 * azp) << 14) + ((y0 + ly) << 7) + x0 + lx;
#pragma unroll
        for (int h = 0; h < 2; ++h) {
            int m3 = (vox0 + (h << 14)) * 3;
            pf[m3] = (h ? acc[0][zp].y : acc[0][zp].x) + b0;
            pf[m3 + 1] = (h ? acc[1][zp].y : acc[1][zp].x) + b1;
            pf[m3 + 2] = (h ? acc[2][zp].y : acc[2][zp].x) + b2;
        }
    }
}

// ------- K2: downsample(127/63) + 1/256 scale, 128^3 -> 64^3 ---------------
// Corner base clamped to <=126/dim (coord exactly 127.0 -> i=126,t=1.0 ==
// reference's zero-weight masked corner, exact).
__global__ __launch_bounds__(256) void ds_kernel(const float* __restrict__ pf,
                                                 float* __restrict__ dsf) {
    int i = blockIdx.x * 256 + threadIdx.x;  // 64^3 samples
    int gx = i & 63, gy = (i >> 6) & 63, gz = i >> 12;
    const float s2 = 127.0f / 63.0f;
    const float k = 1.0f / 256.0f;
    float cz = gz * s2, cy = gy * s2, cx = gx * s2;
    int iz = min((int)cz, 126);
    int iy = min((int)cy, 126);
    int ix = min((int)cx, 126);
    float tzf = cz - (float)iz;
    float tyf = cy - (float)iy;
    float txf = cx - (float)ix;
    float wz[2] = {1.0f - tzf, tzf};
    float wy[2] = {1.0f - tyf, tyf};
    float wx[2] = {1.0f - txf, txf};
    int b = ((iz << 14) + (iy << 7) + ix) * 3;
    float v0 = 0.0f, v1 = 0.0f, v2 = 0.0f;
#pragma unroll
    for (int dz = 0; dz < 2; ++dz)
#pragma unroll
        for (int dy = 0; dy < 2; ++dy)
#pragma unroll
            for (int dx = 0; dx < 2; ++dx) {
                float w = wz[dz] * wy[dy] * wx[dx];
                int bb = b + dz * (3 << 14) + dy * (3 << 7) + dx * 3;
                v0 += pf[bb] * w;
                v1 += pf[bb + 1] * w;
                v2 += pf[bb + 2] * w;
            }
    int o3 = i * 3;
    dsf[o3] = v0 * k;
    dsf[o3 + 1] = v1 * k;
    dsf[o3 + 2] = v2 * k;
}

// ------- K3: one integration step, flat global pass ------------------------
// out[i] = f[i] + trisample(f, id + f[i]); f is 3MB interleaved, L2-resident.
__global__ __launch_bounds__(256) void step_kernel(
    const float* __restrict__ gin, float* __restrict__ gout) {
    int i = blockIdx.x * 256 + threadIdx.x;  // 64^3
    int gx = i & 63, gy = (i >> 6) & 63, gz = i >> 12;
    int i3 = i * 3;
    float fz = gin[i3], fy = gin[i3 + 1], fx = gin[i3 + 2];
    float sm[3];
    trisample3i64(gin, gz + fz, gy + fy, gx + fx, sm);
    gout[i3] = fz + sm[0];
    gout[i3 + 1] = fy + sm[1];
    gout[i3 + 2] = fx + sm[2];
}

// ------- K4: upsample(x2 via 63/127 coords) + label warp -------------------
// flow(g) = 2 * trilerp(g7, g*63/127)   (coords in [0,63]; base clamped to
// <=62, t recomputed -> exact at the 63.0 edge). moved(g) = trisample(label,
// g + flow). flow written PLANAR (final output layout).
__global__ __launch_bounds__(256) void f4up_kernel(
    const float* __restrict__ g7, const float* __restrict__ label,
    float* __restrict__ moved, float* __restrict__ flow) {
    int m = blockIdx.x * 256 + threadIdx.x;  // 128^3
    int gx = m & 127, gy = (m >> 7) & 127, gz = m >> 14;
    const float s3 = 63.0f / 127.0f;
    float cz = gz * s3, cy = gy * s3, cx = gx * s3;
    int iz = min((int)cz, 62);
    int iy = min((int)cy, 62);
    int ix = min((int)cx, 62);
    float tz = cz - (float)iz, ty = cy - (float)iy, tx = cx - (float)ix;
    float wz[2] = {1.0f - tz, tz};
    float wy[2] = {1.0f - ty, ty};
    float wx[2] = {1.0f - tx, tx};
    int b = ((iz << 12) + (iy << 6) + ix) * 3;
    float f0 = 0.0f, f1 = 0.0f, f2 = 0.0f;
#pragma unroll
    for (int dz = 0; dz < 2; ++dz)
#pragma unroll
        for (int dy = 0; dy < 2; ++dy)
#pragma unroll
            for (int dx = 0; dx < 2; ++dx) {
                float w = wz[dz] * wy[dy] * wx[dx];
                int bb = b + dz * (3 << 12) + dy * (3 << 6) + dx * 3;
                f0 += g7[bb] * w;
                f1 += g7[bb + 1] * w;
                f2 += g7[bb + 2] * w;
            }
    float fz = 2.0f * f0, fy = 2.0f * f1, fx = 2.0f * f2;
    flow[m] = fz;
    flow[m + V128] = fy;
    flow[m + 2 * V128] = fx;
    float mv[1];
    trisample<1>(label, 128, 128, 128, 0, gz + fz, gy + fy, gx + fx, mv);
    moved[m] = mv[0];
}

extern "C" void kernel_launch(void* const* d_in, const int* in_sizes, int n_in,
                              void* d_out, int out_size, void* d_ws,
                              size_t ws_size, hipStream_t stream) {
    const float* features = (const float*)d_in[0];
    const float* label = (const float*)d_in[1];
    const float* weight = (const float*)d_in[2];
    const float* bias = (const float*)d_in[3];
    float* out = (float*)d_out;
    float* moved = out;        // 128^3 floats (written by f4up)
    float* flow = out + V128;  // 3*128^3; pf scratch (interleaved), then final
    float* fA = (float*)d_ws;            // 3*64^3 floats, interleaved
    float* fB = fA + 3 * V64;            // 3*64^3 floats, interleaved

    conv_kernel<<<dim3(4, 32, 16), 256, 0, stream>>>(features, weight, bias,
                                                     flow);
    ds_kernel<<<dim3(1024), 256, 0, stream>>>(flow, fB);      // f0 -> fB
    step_kernel<<<dim3(1024), 256, 0, stream>>>(fB, fA);      // s1
    step_kernel<<<dim3(1024), 256, 0, stream>>>(fA, fB);      // s2
    step_kernel<<<dim3(1024), 256, 0, stream>>>(fB, fA);      // s3
    step_kernel<<<dim3(1024), 256, 0, stream>>>(fA, fB);      // s4
    step_kernel<<<dim3(1024), 256, 0, stream>>>(fB, fA);      // s5
    step_kernel<<<dim3(1024), 256, 0, stream>>>(fA, fB);      // s6
    step_kernel<<<dim3(1024), 256, 0, stream>>>(fB, fA);      // s7
    f4up_kernel<<<dim3(8192), 256, 0, stream>>>(fA, label, moved, flow);
}